// Round 10
// baseline (3797.556 us; speedup 1.0000x reference)
//
#include <hip/hip_runtime.h>

#define HH 512
#define II 256
#define TT 512
#define BB 64

typedef unsigned short u16;
typedef unsigned int u32;
typedef unsigned long long u64;
typedef __bf16 bf16x8 __attribute__((ext_vector_type(8)));
typedef u16 u16x8 __attribute__((ext_vector_type(8)));
typedef float f32x4 __attribute__((ext_vector_type(4)));
typedef int i32x4 __attribute__((ext_vector_type(4)));

// raw buffer load with explicit cache policy (aux=1 -> sc0: L1-bypass, L2-served)
__device__ i32x4 llvm_amdgcn_raw_buffer_load_i32x4(i32x4 srsrc, int voffset,
                                                   int soffset, int aux)
    __asm("llvm.amdgcn.raw.buffer.load.v4i32");

struct GruParams {
  const float* Wih[4];  // cell order: 0=f0, 1=b0, 2=f1, 3=b1
  const float* Whh[4];
  const float* bih[4];
  const float* bhh[4];
  const u16* xbf;   // [64][512][256] bf16 (immutable after cvt_x)
  u16* hbuf;        // ring: [4 cells][4 slots][64][512] bf16 (XCD-L2 resident)
  u32* bar;         // [0..255] fast flags; [320] ctr; [384..639] xcds;
                    // [768..1023] mirror flags
  float* out;       // 64*512*1024 + 64*1024
};

__device__ __forceinline__ u16 f2bf(float f) {
  u32 u = __builtin_bit_cast(u32, f);
  u += 0x7fffu + ((u >> 16) & 1u);
  return (u16)(u >> 16);
}

__device__ __forceinline__ float sigm(float x) {
  return 1.0f / (1.0f + __expf(-x));
}

__device__ __forceinline__ float tanh_s(float x) {
  float t = __expf(-2.0f * fabsf(x));
  float r = (1.0f - t) / (1.0f + t);
  return copysignf(r, x);
}

__global__ void cvt_x(const float* __restrict__ x, u16* __restrict__ xb) {
  const int i = blockIdx.x * blockDim.x + threadIdx.x;
  const float4 v = reinterpret_cast<const float4*>(x)[i];
  ushort4 o;
  o.x = f2bf(v.x); o.y = f2bf(v.y); o.z = f2bf(v.z); o.w = f2bf(v.w);
  reinterpret_cast<ushort4*>(xb)[i] = o;
}

// 256 WGs, 1/CU. Self-timed dataflow (R9 transport) + dependency-ordered
// split GEMM: each wave computes flag-free k-blocks first, polls only the
// flags that gate the NEXT block group, then finishes. Layer-1's own-half
// GEMM overlaps layer-0's production tail.
__global__ __launch_bounds__(256, 1) void gru_persist(GruParams p) {
  const int tid  = threadIdx.x;
  const int lane = tid & 63;
  const int wid  = tid >> 6;

  __shared__ float gsm[4][16][33];
  __shared__ u32 role_sm;

  // ---- discovery: measure physical XCD, group same-XCD WGs ----
  u32 xcd;
  asm volatile("s_getreg_b32 %0, hwreg(HW_REG_XCC_ID)" : "=s"(xcd));
  xcd &= 7u;
  u32* ctr  = p.bar + 320;
  u32* xcds = p.bar + 384;
  if (tid == 0) xcds[blockIdx.x] = xcd;
  __syncthreads();
  if (tid == 0) {
    __hip_atomic_fetch_add(ctr, 1u, __ATOMIC_RELEASE, __HIP_MEMORY_SCOPE_AGENT);
    while (__hip_atomic_load(ctr, __ATOMIC_RELAXED, __HIP_MEMORY_SCOPE_AGENT) < 256u) {}
    (void)__hip_atomic_load(ctr, __ATOMIC_ACQUIRE, __HIP_MEMORY_SCOPE_AGENT);
    u32 rank = 0;
    for (int w = 0; w < 256; ++w) {
      const u32 xw = xcds[w];
      if (xw == xcd && w < (int)blockIdx.x) rank++;
    }
    role_sm = rank;
  }
  __syncthreads();

  const u32 rank = role_sm;                    // 0..31 within this XCD
  const int cell = (xcd < 4) ? (rank < 16 ? 0 : 2) : (rank < 16 ? 1 : 3);
  const int mm   = (int)(xcd & 3u);
  const int cc   = (int)(rank & 15u);

  const int KIN  = (cell < 2) ? II : HH;
  const int n16  = lane & 15;
  const int kg   = (lane >> 4) & 3;
  const int koff = kg * 8;
  const int gb   = (wid == 0) ? 0 : (wid == 1) ? HH : 2 * HH;
  const int nbase = gb + cc * 32;

  int nk, inp_end;
  if (wid < 2)       { nk = (KIN + HH) / 32; inp_end = KIN; }
  else if (wid == 2) { nk = KIN / 32;        inp_end = KIN; }
  else               { nk = HH / 32;         inp_end = 0;   }
  const int nblk   = nk / 8;          // 256-wide k blocks
  const int ie_blk = inp_end / 256;   // blocks belonging to the "input" part

  // phase ranges (dependency-ordered)
  int p1b, p1e, p2b, p2e;
  if (cell < 2) {  // layer0: phase1 = x blocks (flag-free), phase2 = h blocks
    p1b = 0;      p1e = (ie_blk < nblk) ? ie_blk : nblk;
    p2b = ie_blk; p2e = nblk;
  } else {         // layer1: phase1 = own-h blocks, phase2 = gi blocks
    p1b = ie_blk; p1e = nblk;
    p2b = 0;      p2e = (ie_blk < nblk) ? ie_blk : nblk;
  }

  float bias0, bias1;
  {
    const int n0 = nbase + n16, n1 = nbase + 16 + n16;
    if (wid < 2)       { bias0 = p.bih[cell][n0] + p.bhh[cell][n0];
                         bias1 = p.bih[cell][n1] + p.bhh[cell][n1]; }
    else if (wid == 2) { bias0 = p.bih[cell][n0]; bias1 = p.bih[cell][n1]; }
    else               { bias0 = p.bhh[cell][n0]; bias1 = p.bhh[cell][n1]; }
  }

  // SRSRC over hbuf ring (1 MiB)
  i32x4 hrs;
  hrs[0] = (int)(u32)(uintptr_t)p.hbuf;
  hrs[1] = (int)(u32)(((u64)(uintptr_t)p.hbuf) >> 32);
  hrs[2] = (int)(4 * 4 * BB * HH * 2);
  hrs[3] = 0x00020000;

  // ---- persistent weight fragments: wf[ks][ntile], B[k][n] layout ----
  bf16x8 wf[32][2];
  {
    const float* Wih = p.Wih[cell];
    const float* Whh = p.Whh[cell];
    #pragma unroll
    for (int ks = 0; ks < 32; ++ks) {
      if (ks < nk) {
        const int kk = ks * 32;
        #pragma unroll
        for (int j = 0; j < 2; ++j) {
          const int r = nbase + 16 * j + n16;
          u16x8 t;
          if (kk < inp_end) {
            const int col = kk + koff;
            if (cell == 1) {  // b0: feature-flipped input -> flip Wih columns
              #pragma unroll
              for (int e = 0; e < 8; ++e)
                t[e] = f2bf(Wih[r * KIN + (KIN - 1 - (col + e))]);
            } else {
              const float4 a = *reinterpret_cast<const float4*>(Wih + r * KIN + col);
              const float4 b = *reinterpret_cast<const float4*>(Wih + r * KIN + col + 4);
              t[0]=f2bf(a.x); t[1]=f2bf(a.y); t[2]=f2bf(a.z); t[3]=f2bf(a.w);
              t[4]=f2bf(b.x); t[5]=f2bf(b.y); t[6]=f2bf(b.z); t[7]=f2bf(b.w);
            }
          } else {
            const int col = kk - inp_end + koff;
            const float4 a = *reinterpret_cast<const float4*>(Whh + r * HH + col);
            const float4 b = *reinterpret_cast<const float4*>(Whh + r * HH + col + 4);
            t[0]=f2bf(a.x); t[1]=f2bf(a.y); t[2]=f2bf(a.z); t[3]=f2bf(a.w);
            t[4]=f2bf(b.x); t[5]=f2bf(b.y); t[6]=f2bf(b.z); t[7]=f2bf(b.w);
          }
          wf[ks][j] = __builtin_bit_cast(bf16x8, t);
        }
        __builtin_amdgcn_sched_barrier(0);
      }
    }
  }

  u32* flF = p.bar + xcd * 32;        // fast flags: this XCD's 32 words (L2)
  u32* flM = p.bar + 768 + xcd * 32;  // mirror flags (agent/L3)
  const int brow = mm * 16 + n16;
  float h0r = 0.0f, h1r = 0.0f;

  for (int tc = 0; tc < TT; ++tc) {
    const int inp_off = (cell >= 2)
      ? (((cell - 2) * 4 + (tc & 3)) * BB + brow) * HH : 0;
    const int own_off = ((cell * 4 + ((tc - 1) & 3)) * BB + brow) * HH;
    const u16* xrow = p.xbf + (size_t)(brow * TT + tc) * II;

    f32x4 acc00 = {bias0, bias0, bias0, bias0};
    f32x4 acc01 = {bias1, bias1, bias1, bias1};
    f32x4 acc10 = {0.f, 0.f, 0.f, 0.f};
    f32x4 acc11 = {0.f, 0.f, 0.f, 0.f};

    // poll lanes 0..31 check this XCD's 32 flags against per-half thresholds
    auto poll2 = [&](int thrLo, int thrHi) {
      const int l31 = lane & 31;
      const int thr = (l31 < 16) ? thrLo : thrHi;
      const u64 fa = (u64)(uintptr_t)(flF + l31);
      int it = 0;
      while (true) {
        u32 v;
        asm volatile("global_load_dword %0, %1, off sc0\n\t"
                     "s_waitcnt vmcnt(0)"
                     : "=v"(v) : "v"(fa) : "memory");
        const bool ok = (lane >= 32) || ((int)v >= thr);
        if (__all((int)ok)) break;
        if (++it >= 8) {
          it = 0;
          const u32 w = __hip_atomic_load(flM + l31, __ATOMIC_RELAXED,
                                          __HIP_MEMORY_SCOPE_AGENT);
          const bool okm = (lane >= 32) || ((int)w >= thr);
          if (__all((int)okm)) break;
        }
      }
    };

    auto gemm_blocks = [&](int bS, int bE) {
      #pragma unroll
      for (int blk = 0; blk < 4; ++blk) {
        if (blk >= bS && blk < bE && blk * 256 < nk * 32) {
          const int kb = blk * 256;
          const bool is_x = (cell < 2) && (kb < inp_end);
          const int hoff = ((kb < inp_end) ? (inp_off + kb)
                                           : (own_off + (kb - inp_end))) + koff;
          #pragma unroll
          for (int u = 0; u < 8; ++u) {
            bf16x8 af;
            if (is_x) {
              af = __builtin_bit_cast(bf16x8,
                  *reinterpret_cast<const uint4*>(xrow + kb + koff + u * 32));
            } else {
              af = __builtin_bit_cast(bf16x8,
                  llvm_amdgcn_raw_buffer_load_i32x4(hrs, 2 * (hoff + u * 32), 0, 1));
            }
            if (u & 1) {
              acc10 = __builtin_amdgcn_mfma_f32_16x16x32_bf16(af, wf[blk*8+u][0], acc10, 0, 0, 0);
              acc11 = __builtin_amdgcn_mfma_f32_16x16x32_bf16(af, wf[blk*8+u][1], acc11, 0, 0, 0);
            } else {
              acc00 = __builtin_amdgcn_mfma_f32_16x16x32_bf16(af, wf[blk*8+u][0], acc00, 0, 0, 0);
              acc01 = __builtin_amdgcn_mfma_f32_16x16x32_bf16(af, wf[blk*8+u][1], acc01, 0, 0, 0);
            }
          }
        }
      }
    };

    if (cell < 2) {
      // layer0: x blocks need no flags at all -> compute first
      gemm_blocks(p1b, p1e);
      if (p2b < p2e) poll2(tc, tc - 3);   // own-cell h(t-1) + ring safety
      gemm_blocks(p2b, p2e);
    } else {
      // layer1: own-h half first (own flags: convoy, usually set), then the
      // only fresh dependency: layer0 finished step tc (flag >= tc+1)
      if (p1b < p1e) poll2(tc, tc);
      gemm_blocks(p1b, p1e);
      if (p2b < p2e) poll2(tc + 1, tc);
      gemm_blocks(p2b, p2e);
    }

    #pragma unroll
    for (int i = 0; i < 4; ++i) {
      gsm[wid][kg * 4 + i][n16]      = acc00[i] + acc10[i];
      gsm[wid][kg * 4 + i][16 + n16] = acc01[i] + acc11[i];
    }
    __syncthreads();

    // ---- epilogue: gates, h update, h-chunk store into ring slot tc&3 ----
    #pragma unroll
    for (int q = 0; q < 2; ++q) {
      const int e = tid + q * 256;
      const int row = e >> 5, col = e & 31;
      const float rr = sigm(gsm[0][row][col]);
      const float zz = sigm(gsm[1][row][col]);
      const float nn = tanh_s(gsm[2][row][col] + rr * gsm[3][row][col]);
      const float hp = q ? h1r : h0r;
      const float hn = (1.0f - zz) * nn + zz * hp;
      if (q) h1r = hn; else h0r = hn;
      const int gbrow = mm * 16 + row;
      const int hc = cc * 32 + col;
      p.hbuf[(size_t)((cell * 4 + (tc & 3)) * BB + gbrow) * HH + hc] = f2bf(hn);
    }
    // drain h to the XCD-local L2, then publish the flag (dual-path)
    asm volatile("s_waitcnt vmcnt(0)" ::: "memory");
    __syncthreads();
    if (tid == 0) {
      const u32 nv = (u32)(tc + 1);
      __hip_atomic_store(flM + rank, nv, __ATOMIC_RELAXED,
                         __HIP_MEMORY_SCOPE_AGENT);          // mirror (L3)
      const u64 fa0 = (u64)(uintptr_t)(flF + rank);
      asm volatile("global_store_dword %0, %1, off sc0"
                   :: "v"(fa0), "v"(nv) : "memory");         // fast (local L2)
    }
    __syncthreads();   // gsm reuse fence for next iteration

    // ---- out stores (off the dependency chain) ----
    if (cell >= 2) {
      #pragma unroll
      for (int q = 0; q < 2; ++q) {
        const int e = tid + q * 256;
        const int row = e >> 5, col = e & 31;
        const int gbrow = mm * 16 + row;
        const int jb = ((cell == 2) ? 0 : HH) + cc * 32 + col;
        const float hv = q ? h1r : h0r;
        __builtin_nontemporal_store(hv,
            p.out + (size_t)(gbrow * TT + tc) * 1024 + jb);
        if (tc == TT - 1)
          p.out[(size_t)BB * TT * 1024 + (size_t)gbrow * 1024 + jb] = hv;
      }
    }
  }
}

extern "C" void kernel_launch(void* const* d_in, const int* in_sizes, int n_in,
                              void* d_out, int out_size, void* d_ws, size_t ws_size,
                              hipStream_t stream) {
  (void)in_sizes; (void)n_in; (void)out_size; (void)ws_size;
  GruParams prm;
  // d_in order: 0:x, then f0(1-4), f1(5-8), b0(9-12), b1(13-16)
  prm.Wih[0] = (const float*)d_in[1];  prm.Whh[0] = (const float*)d_in[2];
  prm.bih[0] = (const float*)d_in[3];  prm.bhh[0] = (const float*)d_in[4];
  prm.Wih[2] = (const float*)d_in[5];  prm.Whh[2] = (const float*)d_in[6];
  prm.bih[2] = (const float*)d_in[7];  prm.bhh[2] = (const float*)d_in[8];
  prm.Wih[1] = (const float*)d_in[9];  prm.Whh[1] = (const float*)d_in[10];
  prm.bih[1] = (const float*)d_in[11]; prm.bhh[1] = (const float*)d_in[12];
  prm.Wih[3] = (const float*)d_in[13]; prm.Whh[3] = (const float*)d_in[14];
  prm.bih[3] = (const float*)d_in[15]; prm.bhh[3] = (const float*)d_in[16];

  const size_t XBF_BYTES  = (size_t)BB * TT * II * 2;          // 16 MiB
  const size_t HBUF_BYTES = (size_t)4 * 4 * BB * HH * 2;       // 1 MiB ring
  u16* xbf  = (u16*)d_ws;
  u16* hbuf = (u16*)((char*)d_ws + XBF_BYTES);
  u32* bar  = (u32*)((char*)d_ws + XBF_BYTES + HBUF_BYTES);

  prm.xbf = xbf; prm.hbuf = hbuf; prm.bar = bar; prm.out = (float*)d_out;

  // zero h ring + all flag/counter words (re-zeroed every replay)
  hipMemsetAsync((char*)d_ws + XBF_BYTES, 0, HBUF_BYTES + 4096, stream);

  const float* x = (const float*)d_in[0];
  cvt_x<<<dim3((BB * TT * II / 4) / 256), dim3(256), 0, stream>>>(x, xbf);

  void* args[] = { &prm };
  hipError_t err = hipLaunchCooperativeKernel((void*)gru_persist, dim3(256), dim3(256),
                                              args, 0, stream);
  if (err != hipSuccess) {
    // fallback: plain launch (256 WGs on 256 CUs -> co-resident)
    hipLaunchKernelGGL(gru_persist, dim3(256), dim3(256), 0, stream, prm);
  }
}

// Round 12
// 2589.845 us; speedup vs baseline: 1.4663x; 1.4663x over previous
//
#include <hip/hip_runtime.h>

#define HH 512
#define II 256
#define TT 512
#define BB 64

typedef unsigned short u16;
typedef unsigned int u32;
typedef unsigned long long u64;
typedef __bf16 bf16x8 __attribute__((ext_vector_type(8)));
typedef u16 u16x8 __attribute__((ext_vector_type(8)));
typedef float f32x4 __attribute__((ext_vector_type(4)));

struct GruParams {
  const float* Wih[4];  // cell order: 0=f0, 1=b0, 2=f1, 3=b1
  const float* Whh[4];
  const float* bih[4];
  const float* bhh[4];
  const u16* xbf;   // [64][512][256] bf16 (immutable after cvt_x)
  u16* hbuf;        // [4 cells][2 parity][64][512] bf16
  u32* bar;         // [xcd*32]: per-XCD step counter; [256] ctr; [257..512] xcds
  float* out;       // 64*512*1024 + 64*1024
};

__device__ __forceinline__ u16 f2bf(float f) {
  u32 u = __builtin_bit_cast(u32, f);
  u += 0x7fffu + ((u >> 16) & 1u);
  return (u16)(u >> 16);
}

__device__ __forceinline__ float sigm(float x) {
  return 1.0f / (1.0f + __expf(-x));
}

__device__ __forceinline__ float tanh_s(float x) {
  float t = __expf(-2.0f * fabsf(x));
  float r = (1.0f - t) / (1.0f + t);
  return copysignf(r, x);
}

__global__ void cvt_x(const float* __restrict__ x, u16* __restrict__ xb) {
  const int i = blockIdx.x * blockDim.x + threadIdx.x;
  const float4 v = reinterpret_cast<const float4*>(x)[i];
  ushort4 o;
  o.x = f2bf(v.x); o.y = f2bf(v.y); o.z = f2bf(v.z); o.w = f2bf(v.w);
  reinterpret_cast<ushort4*>(xb)[i] = o;
}

// 256 WGs, 1/CU (R6 structure, best known good). Roles derived from measured
// XCD so each (pair, mm) sync domain = the 32 WGs of ONE XCD -> all cross-WG
// traffic is same-XCD L2. ONLY change vs R6: the barrier's two atomics use
// inline-asm sc0-only (sc1=0) -> they execute at the LOCAL L2 (~250cy) instead
// of agent scope/L3 (~800cy). 4 waves: wid 0=r,1=z,2=i_n,3=h_n.
__global__ __launch_bounds__(256, 1) void gru_persist(GruParams p) {
  const int tid  = threadIdx.x;
  const int lane = tid & 63;
  const int wid  = tid >> 6;

  __shared__ float gsm[4][16][33];    // pad 33
  __shared__ u32 role_sm;

  // ---- discovery: measure physical XCD, group same-XCD WGs ----
  u32 xcd;
  asm volatile("s_getreg_b32 %0, hwreg(HW_REG_XCC_ID)" : "=s"(xcd));
  xcd &= 7u;
  u32* ctr  = p.bar + 256;
  u32* xcds = p.bar + 257;
  if (tid == 0) xcds[blockIdx.x] = xcd;
  __syncthreads();
  if (tid == 0) {
    __hip_atomic_fetch_add(ctr, 1u, __ATOMIC_RELEASE, __HIP_MEMORY_SCOPE_AGENT);
    while (__hip_atomic_load(ctr, __ATOMIC_RELAXED, __HIP_MEMORY_SCOPE_AGENT) < 256u) {}
    (void)__hip_atomic_load(ctr, __ATOMIC_ACQUIRE, __HIP_MEMORY_SCOPE_AGENT);
    u32 rank = 0;
    for (int w = 0; w < 256; ++w) {
      const u32 xw = xcds[w];
      if (xw == xcd && w < (int)blockIdx.x) rank++;
    }
    role_sm = rank;
  }
  __syncthreads();

  const u32 rank = role_sm;                    // 0..31 within this XCD
  const int cell = (xcd < 4) ? (rank < 16 ? 0 : 2) : (rank < 16 ? 1 : 3);
  const int mm   = (int)(xcd & 3u);
  const int cc   = (int)(rank & 15u);

  const int KIN  = (cell < 2) ? II : HH;
  const int n16  = lane & 15;
  const int kg   = (lane >> 4) & 3;
  const int koff = kg * 8;
  const int gb   = (wid == 0) ? 0 : (wid == 1) ? HH : 2 * HH;
  const int nbase = gb + cc * 32;

  int nk, inp_end;
  if (wid < 2)       { nk = (KIN + HH) / 32; inp_end = KIN; }
  else if (wid == 2) { nk = KIN / 32;        inp_end = KIN; }
  else               { nk = HH / 32;         inp_end = 0;   }

  float bias0, bias1;
  {
    const int n0 = nbase + n16, n1 = nbase + 16 + n16;
    if (wid < 2)       { bias0 = p.bih[cell][n0] + p.bhh[cell][n0];
                         bias1 = p.bih[cell][n1] + p.bhh[cell][n1]; }
    else if (wid == 2) { bias0 = p.bih[cell][n0]; bias1 = p.bih[cell][n1]; }
    else               { bias0 = p.bhh[cell][n0]; bias1 = p.bhh[cell][n1]; }
  }

  // ---- persistent weight fragments: wf[ks][ntile], B[k][n] layout ----
  bf16x8 wf[32][2];
  {
    const float* Wih = p.Wih[cell];
    const float* Whh = p.Whh[cell];
    #pragma unroll
    for (int ks = 0; ks < 32; ++ks) {
      if (ks < nk) {
        const int kk = ks * 32;
        #pragma unroll
        for (int j = 0; j < 2; ++j) {
          const int r = nbase + 16 * j + n16;
          u16x8 t;
          if (kk < inp_end) {
            const int col = kk + koff;
            if (cell == 1) {  // b0: feature-flipped input -> flip Wih columns
              #pragma unroll
              for (int e = 0; e < 8; ++e)
                t[e] = f2bf(Wih[r * KIN + (KIN - 1 - (col + e))]);
            } else {
              const float4 a = *reinterpret_cast<const float4*>(Wih + r * KIN + col);
              const float4 b = *reinterpret_cast<const float4*>(Wih + r * KIN + col + 4);
              t[0]=f2bf(a.x); t[1]=f2bf(a.y); t[2]=f2bf(a.z); t[3]=f2bf(a.w);
              t[4]=f2bf(b.x); t[5]=f2bf(b.y); t[6]=f2bf(b.z); t[7]=f2bf(b.w);
            }
          } else {
            const int col = kk - inp_end + koff;
            const float4 a = *reinterpret_cast<const float4*>(Whh + r * HH + col);
            const float4 b = *reinterpret_cast<const float4*>(Whh + r * HH + col + 4);
            t[0]=f2bf(a.x); t[1]=f2bf(a.y); t[2]=f2bf(a.z); t[3]=f2bf(a.w);
            t[4]=f2bf(b.x); t[5]=f2bf(b.y); t[6]=f2bf(b.z); t[7]=f2bf(b.w);
          }
          wf[ks][j] = __builtin_bit_cast(bf16x8, t);
        }
        __builtin_amdgcn_sched_barrier(0);
      }
    }
  }

  u32* dctr = p.bar + xcd * 32;     // this XCD's step counter: own 128B line
  const int brow = mm * 16 + n16;   // this lane's A-operand batch row
  float h0r = 0.0f, h1r = 0.0f;     // fp32 master h for this thread's 2 elements

  for (int s = 0; s <= TT; ++s) {
    const int tc = (cell < 2) ? s : s - 1;   // layer-1 runs one step skewed
    const bool active = (tc >= 0) && (tc < TT);
    if (active) {
      const u16* inp_base = (cell < 2)
        ? p.xbf + (size_t)(brow * TT + tc) * II
        : p.hbuf + (size_t)(((cell - 2) * 2 + (tc & 1)) * BB + brow) * HH;
      const u16* own_base =
          p.hbuf + (size_t)((cell * 2 + ((tc & 1) ^ 1)) * BB + brow) * HH;

      f32x4 acc00 = {bias0, bias0, bias0, bias0};
      f32x4 acc01 = {bias1, bias1, bias1, bias1};
      f32x4 acc10 = {0.f, 0.f, 0.f, 0.f};
      f32x4 acc11 = {0.f, 0.f, 0.f, 0.f};

      #pragma unroll
      for (int blk = 0; blk < 4; ++blk) {
        if (blk * 256 < nk * 32) {
          const int kb = blk * 256;
          const u16* bp = (kb < inp_end) ? (inp_base + kb + koff)
                                         : (own_base + (kb - inp_end) + koff);
          #pragma unroll
          for (int u = 0; u < 8; ++u) {
            const bf16x8 af = __builtin_bit_cast(bf16x8,
                *reinterpret_cast<const uint4*>(bp + u * 32));
            if (u & 1) {
              acc10 = __builtin_amdgcn_mfma_f32_16x16x32_bf16(af, wf[blk*8+u][0], acc10, 0, 0, 0);
              acc11 = __builtin_amdgcn_mfma_f32_16x16x32_bf16(af, wf[blk*8+u][1], acc11, 0, 0, 0);
            } else {
              acc00 = __builtin_amdgcn_mfma_f32_16x16x32_bf16(af, wf[blk*8+u][0], acc00, 0, 0, 0);
              acc01 = __builtin_amdgcn_mfma_f32_16x16x32_bf16(af, wf[blk*8+u][1], acc01, 0, 0, 0);
            }
          }
        }
      }
      #pragma unroll
      for (int i = 0; i < 4; ++i) {
        gsm[wid][kg * 4 + i][n16]      = acc00[i] + acc10[i];
        gsm[wid][kg * 4 + i][16 + n16] = acc01[i] + acc11[i];
      }
    }
    __syncthreads();
    if (active) {
      #pragma unroll
      for (int q = 0; q < 2; ++q) {
        const int e = tid + q * 256;
        const int row = e >> 5, col = e & 31;
        const float rr = sigm(gsm[0][row][col]);
        const float zz = sigm(gsm[1][row][col]);
        const float nn = tanh_s(gsm[2][row][col] + rr * gsm[3][row][col]);
        const float hp = q ? h1r : h0r;
        const float hn = (1.0f - zz) * nn + zz * hp;
        if (q) h1r = hn; else h0r = hn;
        const int gbrow = mm * 16 + row;
        const int hc = cc * 32 + col;
        // plain store: write-through -> lands in this XCD's L2 (coherent for
        // the 32 same-XCD consumer WGs)
        p.hbuf[(size_t)((cell * 2 + (tc & 1)) * BB + gbrow) * HH + hc] = f2bf(hn);
      }
    }
    // ---- same-XCD step barrier: vmcnt(0) drains h to the local L2, then
    //      arrival + poll via sc0-only atomics (sc1=0 -> execute AT the local
    //      L2, the coherence point of this domain; ~3x lower latency than the
    //      agent-scope/L3 form). Last arriver skips the poll entirely.
    //      buffer_inv (L1-only) before consumers reload h with plain loads.
    if (s < TT) {
      asm volatile("s_waitcnt vmcnt(0)" ::: "memory");
      __syncthreads();
      if (wid == 0) {
        if (lane == 0) {
          const u64 fa = (u64)(uintptr_t)dctr;
          const u32 tgt = 32u * (u32)(s + 1);
          u32 seen;
          asm volatile("global_atomic_add %0, %1, %2, off sc0\n\t"
                       "s_waitcnt vmcnt(0)"
                       : "=v"(seen) : "v"(fa), "v"(1u) : "memory");
          seen += 1u;
          while (seen < tgt) {
            asm volatile("global_atomic_add %0, %1, %2, off sc0\n\t"
                         "s_waitcnt vmcnt(0)"
                         : "=v"(seen) : "v"(fa), "v"(0u) : "memory");
          }
        }
        asm volatile("buffer_inv sc0" ::: "memory");  // L1-only invalidate
      }
      __syncthreads();
    }
    // ---- out stores AFTER the barrier: HBM ack hides under next compute ----
    if (active && cell >= 2) {
      #pragma unroll
      for (int q = 0; q < 2; ++q) {
        const int e = tid + q * 256;
        const int row = e >> 5, col = e & 31;
        const int gbrow = mm * 16 + row;
        const int jb = ((cell == 2) ? 0 : HH) + cc * 32 + col;
        const float hv = q ? h1r : h0r;
        __builtin_nontemporal_store(hv,
            p.out + (size_t)(gbrow * TT + tc) * 1024 + jb);
        if (tc == TT - 1)
          p.out[(size_t)BB * TT * 1024 + (size_t)gbrow * 1024 + jb] = hv;
      }
    }
  }
}

extern "C" void kernel_launch(void* const* d_in, const int* in_sizes, int n_in,
                              void* d_out, int out_size, void* d_ws, size_t ws_size,
                              hipStream_t stream) {
  (void)in_sizes; (void)n_in; (void)out_size; (void)ws_size;
  GruParams prm;
  // d_in order: 0:x, then f0(1-4), f1(5-8), b0(9-12), b1(13-16)
  prm.Wih[0] = (const float*)d_in[1];  prm.Whh[0] = (const float*)d_in[2];
  prm.bih[0] = (const float*)d_in[3];  prm.bhh[0] = (const float*)d_in[4];
  prm.Wih[2] = (const float*)d_in[5];  prm.Whh[2] = (const float*)d_in[6];
  prm.bih[2] = (const float*)d_in[7];  prm.bhh[2] = (const float*)d_in[8];
  prm.Wih[1] = (const float*)d_in[9];  prm.Whh[1] = (const float*)d_in[10];
  prm.bih[1] = (const float*)d_in[11]; prm.bhh[1] = (const float*)d_in[12];
  prm.Wih[3] = (const float*)d_in[13]; prm.Whh[3] = (const float*)d_in[14];
  prm.bih[3] = (const float*)d_in[15]; prm.bhh[3] = (const float*)d_in[16];

  const size_t XBF_BYTES  = (size_t)BB * TT * II * 2;      // 16 MiB
  const size_t HBUF_BYTES = (size_t)4 * 2 * BB * HH * 2;   // 512 KiB
  u16* xbf  = (u16*)d_ws;
  u16* hbuf = (u16*)((char*)d_ws + XBF_BYTES);
  u32* bar  = (u32*)((char*)d_ws + XBF_BYTES + HBUF_BYTES);

  prm.xbf = xbf; prm.hbuf = hbuf; prm.bar = bar; prm.out = (float*)d_out;

  // zero h state + counters + xcds table (re-zeroed every replay)
  hipMemsetAsync((char*)d_ws + XBF_BYTES, 0, HBUF_BYTES + 4096, stream);

  const float* x = (const float*)d_in[0];
  cvt_x<<<dim3((BB * TT * II / 4) / 256), dim3(256), 0, stream>>>(x, xbf);

  void* args[] = { &prm };
  hipError_t err = hipLaunchCooperativeKernel((void*)gru_persist, dim3(256), dim3(256),
                                              args, 0, stream);
  if (err != hipSuccess) {
    // fallback: plain launch (256 WGs on 256 CUs -> co-resident)
    hipLaunchKernelGGL(gru_persist, dim3(256), dim3(256), 0, stream, prm);
  }
}